// Round 6
// baseline (21.008 us; speedup 1.0000x reference)
//
#include <hip/hip_runtime.h>
#include <float.h>

#define B_TOK 256
#define N_OUT 512
#define K_IN  1024

#define KSPLIT 8
#define KC     (K_IN / KSPLIT)   // 128 k per block
#define BT     16                // b rows per block (4 per wave)
#define NT     64                // n per block (1 per lane)

// ---------------- Stage 1 ----------------
// grid (16 b-groups, 8 n-groups, 8 k-chunks) = 1024 blocks (4/CU = 16 waves/CU).
// Block 256 = 4 waves. LDS: w-tile [64n][128k] XOR-swizzled (32KB) + x-tile
// [16b][128k] linear (8KB). ALL inner-loop operands from LDS (in-order pipe,
// fine-grained lgkmcnt): per 4k-iter/lane = 1 conflict-free w ds_read_b128 +
// 4 wave-uniform (broadcast) x ds_read_b128 -> 16 products = 32 VALU ops.
// Wave wv owns b rows wv*4..wv*4+3 for the full 128-k chunk; no cross-wave
// reduction needed -- each wave writes its own partial rows.
__global__ __launch_bounds__(256)
void mam_stage1(const float* __restrict__ x, const float* __restrict__ w,
                float* __restrict__ pmx, float* __restrict__ pmn) {
    __shared__ float ws[NT * KC];   // 32 KB, swizzled
    __shared__ float xs[BT * KC];   // 8 KB, linear

    const int tid = threadIdx.x;
    const int b0  = blockIdx.x * BT;
    const int n0  = blockIdx.y * NT;
    const int kc  = blockIdx.z * KC;

    // ---- stage w[n0..+63][kc..+127] -> LDS (swizzled 16B chunks) ----
    // thread t: row r=t>>2, chunks c=(t&3)+4j: 4 consecutive lanes read one
    // contiguous 64B line (perfect coalescing); ds_write <=2-way per 8-lane phase.
    {
        const int r  = tid >> 2;
        const int cb = tid & 3;
        const float* gsrc = w + (size_t)(n0 + r) * K_IN + kc;
#pragma unroll
        for (int j = 0; j < 8; ++j) {
            const int c = cb + 4 * j;
            const float4 v = *reinterpret_cast<const float4*>(gsrc + c * 4);
            *reinterpret_cast<float4*>(&ws[r * KC + ((c ^ (r & 7)) << 2)]) = v;
        }
    }
    // ---- stage x[b0..+15][kc..+127] -> LDS (linear; broadcast-read later) ----
    // thread t: row r=t>>4, chunks c=(t&15)+16j: 16 lanes read 256B contiguous.
    {
        const int r  = tid >> 4;
        const int cb = tid & 15;
        const float* gsrc = x + (size_t)(b0 + r) * K_IN + kc;
#pragma unroll
        for (int j = 0; j < 2; ++j) {
            const int c = cb + 16 * j;
            const float4 v = *reinterpret_cast<const float4*>(gsrc + c * 4);
            *reinterpret_cast<float4*>(&xs[r * KC + c * 4]) = v;
        }
    }
    __syncthreads();

    // ---- compute ----
    const int wv = __builtin_amdgcn_readfirstlane(tid >> 6);  // 0..3, SGPR
    const int ln = tid & 63;                                  // lane -> n
    const int xr0 = (wv * 4 + 0) * KC;
    const int xr1 = (wv * 4 + 1) * KC;
    const int xr2 = (wv * 4 + 2) * KC;
    const int xr3 = (wv * 4 + 3) * KC;
    const int wrow = ln * KC;
    const int swz  = ln & 7;

    float mx0 = -FLT_MAX, mx1 = -FLT_MAX, mx2 = -FLT_MAX, mx3 = -FLT_MAX;
    float mn0 =  FLT_MAX, mn1 =  FLT_MAX, mn2 =  FLT_MAX, mn3 =  FLT_MAX;

#pragma unroll 8
    for (int c = 0; c < KC / 4; ++c) {            // 32 iters of 4 k
        const float4 wk = *reinterpret_cast<const float4*>(
            &ws[wrow + ((c ^ swz) << 2)]);        // conflict-free b128
        const float4 x0 = *reinterpret_cast<const float4*>(&xs[xr0 + c * 4]);
        const float4 x1 = *reinterpret_cast<const float4*>(&xs[xr1 + c * 4]);
        const float4 x2 = *reinterpret_cast<const float4*>(&xs[xr2 + c * 4]);
        const float4 x3 = *reinterpret_cast<const float4*>(&xs[xr3 + c * 4]);

        {   const float p0 = x0.x * wk.x, p1 = x0.y * wk.y, p2 = x0.z * wk.z, p3 = x0.w * wk.w;
            mx0 = fmaxf(fmaxf(mx0, p0), p1); mx0 = fmaxf(fmaxf(mx0, p2), p3);   // v_max3
            mn0 = fminf(fminf(mn0, p0), p1); mn0 = fminf(fminf(mn0, p2), p3); }
        {   const float p0 = x1.x * wk.x, p1 = x1.y * wk.y, p2 = x1.z * wk.z, p3 = x1.w * wk.w;
            mx1 = fmaxf(fmaxf(mx1, p0), p1); mx1 = fmaxf(fmaxf(mx1, p2), p3);
            mn1 = fminf(fminf(mn1, p0), p1); mn1 = fminf(fminf(mn1, p2), p3); }
        {   const float p0 = x2.x * wk.x, p1 = x2.y * wk.y, p2 = x2.z * wk.z, p3 = x2.w * wk.w;
            mx2 = fmaxf(fmaxf(mx2, p0), p1); mx2 = fmaxf(fmaxf(mx2, p2), p3);
            mn2 = fminf(fminf(mn2, p0), p1); mn2 = fminf(fminf(mn2, p2), p3); }
        {   const float p0 = x3.x * wk.x, p1 = x3.y * wk.y, p2 = x3.z * wk.z, p3 = x3.w * wk.w;
            mx3 = fmaxf(fmaxf(mx3, p0), p1); mx3 = fmaxf(fmaxf(mx3, p2), p3);
            mn3 = fminf(fminf(mn3, p0), p1); mn3 = fminf(fminf(mn3, p2), p3); }
    }

    // ---- write one partial plane per k-chunk (coalesced 256B per row) ----
    const size_t plane = (size_t)B_TOK * N_OUT;
    const size_t base  = (size_t)blockIdx.z * plane
                       + (size_t)(b0 + wv * 4) * N_OUT + n0 + ln;
    pmx[base + 0 * N_OUT] = mx0;  pmn[base + 0 * N_OUT] = mn0;
    pmx[base + 1 * N_OUT] = mx1;  pmn[base + 1 * N_OUT] = mn1;
    pmx[base + 2 * N_OUT] = mx2;  pmn[base + 2 * N_OUT] = mn2;
    pmx[base + 3 * N_OUT] = mx3;  pmn[base + 3 * N_OUT] = mn3;
}

// ---------------- Stage 2: combine 8 planes + bias ----------------
__global__ __launch_bounds__(256)
void mam_stage2(const float* __restrict__ pmx, const float* __restrict__ pmn,
                const float* __restrict__ bias, float* __restrict__ out) {
    const size_t i4 = ((size_t)blockIdx.x * 256 + threadIdx.x) * 4;
    const size_t plane = (size_t)B_TOK * N_OUT;
    float4 MX = *reinterpret_cast<const float4*>(pmx + i4);
    float4 MN = *reinterpret_cast<const float4*>(pmn + i4);
#pragma unroll
    for (int p = 1; p < KSPLIT; ++p) {
        const float4 a = *reinterpret_cast<const float4*>(pmx + (size_t)p * plane + i4);
        const float4 i = *reinterpret_cast<const float4*>(pmn + (size_t)p * plane + i4);
        MX.x = fmaxf(MX.x, a.x); MX.y = fmaxf(MX.y, a.y);
        MX.z = fmaxf(MX.z, a.z); MX.w = fmaxf(MX.w, a.w);
        MN.x = fminf(MN.x, i.x); MN.y = fminf(MN.y, i.y);
        MN.z = fminf(MN.z, i.z); MN.w = fminf(MN.w, i.w);
    }
    const float4 bb = *reinterpret_cast<const float4*>(bias + (i4 & (N_OUT - 1)));
    float4 o;
    o.x = MX.x + MN.x + bb.x; o.y = MX.y + MN.y + bb.y;
    o.z = MX.z + MN.z + bb.z; o.w = MX.w + MN.w + bb.w;
    *reinterpret_cast<float4*>(out + i4) = o;
}

// ---------------- Fallback (workspace too small) ----------------
__global__ __launch_bounds__(256)
void mam_simple(const float* __restrict__ x, const float* __restrict__ w,
                const float* __restrict__ bias, float* __restrict__ out) {
    const int idx = blockIdx.x * 256 + threadIdx.x;
    const int b = idx / N_OUT, n = idx % N_OUT;
    const float* xr = x + (size_t)b * K_IN;
    const float* wr = w + (size_t)n * K_IN;
    float mx = -FLT_MAX, mn = FLT_MAX;
#pragma unroll 4
    for (int k = 0; k < K_IN; k += 4) {
        const float4 xv = *reinterpret_cast<const float4*>(xr + k);
        const float4 wv = *reinterpret_cast<const float4*>(wr + k);
        const float p0 = xv.x * wv.x, p1 = xv.y * wv.y;
        const float p2 = xv.z * wv.z, p3 = xv.w * wv.w;
        mx = fmaxf(fmaxf(mx, p0), p1);
        mx = fmaxf(fmaxf(mx, p2), p3);
        mn = fminf(fminf(mn, p0), p1);
        mn = fminf(fminf(mn, p2), p3);
    }
    out[idx] = mx + mn + bias[n];
}

extern "C" void kernel_launch(void* const* d_in, const int* in_sizes, int n_in,
                              void* d_out, int out_size, void* d_ws, size_t ws_size,
                              hipStream_t stream) {
    const float* x    = (const float*)d_in[0];   // [256,1024]
    const float* w    = (const float*)d_in[1];   // [512,1024]
    const float* bias = (const float*)d_in[2];   // [512]
    float* out = (float*)d_out;                  // [256,512] f32

    const size_t plane = (size_t)B_TOK * N_OUT;
    const size_t need  = 2 * (size_t)KSPLIT * plane * sizeof(float);  // 8 MB

    if (ws_size >= need) {
        float* pmx = (float*)d_ws;
        float* pmn = pmx + (size_t)KSPLIT * plane;
        mam_stage1<<<dim3(B_TOK / BT, N_OUT / NT, KSPLIT), 256, 0, stream>>>(x, w, pmx, pmn);
        mam_stage2<<<(int)(plane / 4 / 256), 256, 0, stream>>>(pmx, pmn, bias, out);
    } else {
        mam_simple<<<(B_TOK * N_OUT) / 256, 256, 0, stream>>>(x, w, bias, out);
    }
}

// Round 7
// 20.923 us; speedup vs baseline: 1.0040x; 1.0040x over previous
//
#include <hip/hip_runtime.h>
#include <float.h>

#define B_TOK 256
#define N_OUT 512
#define K_IN  1024

#define KSPLIT 8
#define KT     (K_IN / KSPLIT)   // 128 k per block
#define BT     16                // b rows per block
#define NT     64                // n cols per block

// ---------------- Stage 1 ----------------
// grid (16 bg, 8 ng, 8 kc) = 1024 blocks (4/CU -> 16 waves/CU); block 256 = 4 waves.
// LDS 40KB: ws[64n][128k] swizzled + xs[16b][128k] swizzled; red aliases ws.
// Waves split k 4-way (32 k each); lane = (bq=ln>>4, nq=ln&15) owns a 4b x 4n
// register tile. Per 4k-iter: 4 w ds_read_b128 + 4 x ds_read_b128 -> 64 products
// (64 mul + 32 max3 + 32 min3). DS-read instrs: 262K total (2.5x less than R6).
// Swizzle: w slot = c ^ (n>>2)  (read: 16 distinct slots across nq -> even banks;
//          write: row-quad-uniform q -> 16 distinct slots across cb -> even).
//          x slot = c ^ b        (read: 4 distinct slots + 16-way broadcast; even).
__global__ __launch_bounds__(256)
void mam_stage1(const float* __restrict__ x, const float* __restrict__ w,
                float* __restrict__ pmx, float* __restrict__ pmn) {
    __shared__ float lds[10240];   // 40 KB
    float* ws = lds;               // [64][128]
    float* xs = lds + 8192;        // [16][128]

    const int tid = threadIdx.x;
    const int wv  = tid >> 6;      // 0..3
    const int ln  = tid & 63;
    const int b0  = blockIdx.x * BT;
    const int n0  = blockIdx.y * NT;
    const int kc  = blockIdx.z * KT;

    // ---- stage w[n0..+63][kc..+127]: slot = c ^ (r>>2) ----
    {
        const int cb = ln & 15;          // chunk low (16B units)
        const int u  = ln >> 4;          // row within quad
#pragma unroll
        for (int p = 0; p < 4; ++p) {
            const int r = 16 * wv + 4 * p + u;     // row-quad base 4-aligned
            const int q = r >> 2;                  // uniform within instr
            const float* src = w + (size_t)(n0 + r) * K_IN + kc;
#pragma unroll
            for (int m = 0; m < 2; ++m) {
                const int c = cb + 16 * m;
                const float4 v = *reinterpret_cast<const float4*>(src + c * 4);
                *reinterpret_cast<float4*>(&ws[r * 128 + ((c ^ q) << 2)]) = v;
            }
        }
    }
    // ---- stage x[b0..+15][kc..+127]: slot = c ^ b ----
    {
        const int cb = ln & 15;
        const int u  = ln >> 4;
        const int b  = 4 * wv + u;                 // 4 rows per wave
        const float* src = x + (size_t)(b0 + b) * K_IN + kc;
#pragma unroll
        for (int m = 0; m < 2; ++m) {
            const int c = cb + 16 * m;
            const float4 v = *reinterpret_cast<const float4*>(src + c * 4);
            *reinterpret_cast<float4*>(&xs[b * 128 + ((c ^ b) << 2)]) = v;
        }
    }
    __syncthreads();

    // ---- compute: wave wv owns chunks c in [8*wv, 8*wv+8) (32 k) ----
    const int nq = ln & 15;    // n-quad: n = 4*nq + j
    const int bq = ln >> 4;    // b-quad: b = 4*bq + i

    float mx[4][4], mn[4][4];  // [i b][j n] - static indices only
#pragma unroll
    for (int i = 0; i < 4; ++i)
#pragma unroll
        for (int j = 0; j < 4; ++j) { mx[i][j] = -FLT_MAX; mn[i][j] = FLT_MAX; }

#pragma unroll 2
    for (int cl = 0; cl < 8; ++cl) {
        const int c = 8 * wv + cl;
        float4 wf[4], xf[4];
#pragma unroll
        for (int j = 0; j < 4; ++j)
            wf[j] = *reinterpret_cast<const float4*>(
                &ws[(4 * nq + j) * 128 + ((c ^ nq) << 2)]);
#pragma unroll
        for (int i = 0; i < 4; ++i)
            xf[i] = *reinterpret_cast<const float4*>(
                &xs[(4 * bq + i) * 128 + ((c ^ (4 * bq + i)) << 2)]);

#pragma unroll
        for (int i = 0; i < 4; ++i) {
#pragma unroll
            for (int j = 0; j < 4; ++j) {
                const float p0 = xf[i].x * wf[j].x;
                const float p1 = xf[i].y * wf[j].y;
                const float p2 = xf[i].z * wf[j].z;
                const float p3 = xf[i].w * wf[j].w;
                mx[i][j] = fmaxf(fmaxf(mx[i][j], p0), p1);   // v_max3
                mx[i][j] = fmaxf(fmaxf(mx[i][j], p2), p3);
                mn[i][j] = fminf(fminf(mn[i][j], p0), p1);   // v_min3
                mn[i][j] = fminf(fminf(mn[i][j], p2), p3);
            }
        }
    }

    // ---- combine 4 wave k-partials via LDS (red aliases ws) ----
    __syncthreads();   // all ws/xs reads done before overwrite
    float* red = lds;  // [4 wv][2 sel][1024 outputs]
#pragma unroll
    for (int i = 0; i < 4; ++i) {
        const int ol = (4 * bq + i) * 64 + 4 * nq;
        float4 a = make_float4(mx[i][0], mx[i][1], mx[i][2], mx[i][3]);
        float4 d = make_float4(mn[i][0], mn[i][1], mn[i][2], mn[i][3]);
        *reinterpret_cast<float4*>(&red[(wv * 2 + 0) * 1024 + ol]) = a;
        *reinterpret_cast<float4*>(&red[(wv * 2 + 1) * 1024 + ol]) = d;
    }
    __syncthreads();

    // ---- 256 threads x 4 outputs: reduce 4 waves, write partial plane ----
    {
        float4 MX = *reinterpret_cast<const float4*>(&red[0 * 1024 + tid * 4]);
        float4 MN = *reinterpret_cast<const float4*>(&red[1 * 1024 + tid * 4]);
#pragma unroll
        for (int v = 1; v < 4; ++v) {
            const float4 a = *reinterpret_cast<const float4*>(&red[(v * 2 + 0) * 1024 + tid * 4]);
            const float4 d = *reinterpret_cast<const float4*>(&red[(v * 2 + 1) * 1024 + tid * 4]);
            MX.x = fmaxf(MX.x, a.x); MX.y = fmaxf(MX.y, a.y);
            MX.z = fmaxf(MX.z, a.z); MX.w = fmaxf(MX.w, a.w);
            MN.x = fminf(MN.x, d.x); MN.y = fminf(MN.y, d.y);
            MN.z = fminf(MN.z, d.z); MN.w = fminf(MN.w, d.w);
        }
        const int bl = tid >> 4;           // output b within tile
        const int nl = (tid & 15) * 4;     // output n within tile
        const size_t o = ((size_t)blockIdx.z * B_TOK + b0 + bl) * N_OUT + n0 + nl;
        *reinterpret_cast<float4*>(&pmx[o]) = MX;
        *reinterpret_cast<float4*>(&pmn[o]) = MN;
    }
}

// ---------------- Stage 2: combine 8 planes + bias ----------------
__global__ __launch_bounds__(256)
void mam_stage2(const float* __restrict__ pmx, const float* __restrict__ pmn,
                const float* __restrict__ bias, float* __restrict__ out) {
    const size_t i4 = ((size_t)blockIdx.x * 256 + threadIdx.x) * 4;
    const size_t plane = (size_t)B_TOK * N_OUT;
    float4 MX = *reinterpret_cast<const float4*>(pmx + i4);
    float4 MN = *reinterpret_cast<const float4*>(pmn + i4);
#pragma unroll
    for (int p = 1; p < KSPLIT; ++p) {
        const float4 a = *reinterpret_cast<const float4*>(pmx + (size_t)p * plane + i4);
        const float4 d = *reinterpret_cast<const float4*>(pmn + (size_t)p * plane + i4);
        MX.x = fmaxf(MX.x, a.x); MX.y = fmaxf(MX.y, a.y);
        MX.z = fmaxf(MX.z, a.z); MX.w = fmaxf(MX.w, a.w);
        MN.x = fminf(MN.x, d.x); MN.y = fminf(MN.y, d.y);
        MN.z = fminf(MN.z, d.z); MN.w = fminf(MN.w, d.w);
    }
    const float4 bb = *reinterpret_cast<const float4*>(bias + (i4 & (N_OUT - 1)));
    float4 o;
    o.x = MX.x + MN.x + bb.x; o.y = MX.y + MN.y + bb.y;
    o.z = MX.z + MN.z + bb.z; o.w = MX.w + MN.w + bb.w;
    *reinterpret_cast<float4*>(out + i4) = o;
}

// ---------------- Fallback (workspace too small) ----------------
__global__ __launch_bounds__(256)
void mam_simple(const float* __restrict__ x, const float* __restrict__ w,
                const float* __restrict__ bias, float* __restrict__ out) {
    const int idx = blockIdx.x * 256 + threadIdx.x;
    const int b = idx / N_OUT, n = idx % N_OUT;
    const float* xr = x + (size_t)b * K_IN;
    const float* wr = w + (size_t)n * K_IN;
    float mx = -FLT_MAX, mn = FLT_MAX;
#pragma unroll 4
    for (int k = 0; k < K_IN; k += 4) {
        const float4 xv = *reinterpret_cast<const float4*>(xr + k);
        const float4 wv = *reinterpret_cast<const float4*>(wr + k);
        const float p0 = xv.x * wv.x, p1 = xv.y * wv.y;
        const float p2 = xv.z * wv.z, p3 = xv.w * wv.w;
        mx = fmaxf(fmaxf(mx, p0), p1);
        mx = fmaxf(fmaxf(mx, p2), p3);
        mn = fminf(fminf(mn, p0), p1);
        mn = fminf(fminf(mn, p2), p3);
    }
    out[idx] = mx + mn + bias[n];
}

extern "C" void kernel_launch(void* const* d_in, const int* in_sizes, int n_in,
                              void* d_out, int out_size, void* d_ws, size_t ws_size,
                              hipStream_t stream) {
    const float* x    = (const float*)d_in[0];   // [256,1024]
    const float* w    = (const float*)d_in[1];   // [512,1024]
    const float* bias = (const float*)d_in[2];   // [512]
    float* out = (float*)d_out;                  // [256,512] f32

    const size_t plane = (size_t)B_TOK * N_OUT;
    const size_t need  = 2 * (size_t)KSPLIT * plane * sizeof(float);  // 8 MB

    if (ws_size >= need) {
        float* pmx = (float*)d_ws;
        float* pmn = pmx + (size_t)KSPLIT * plane;
        mam_stage1<<<dim3(B_TOK / BT, N_OUT / NT, KSPLIT), 256, 0, stream>>>(x, w, pmx, pmn);
        mam_stage2<<<(int)(plane / 4 / 256), 256, 0, stream>>>(pmx, pmn, bias, out);
    } else {
        mam_simple<<<(B_TOK * N_OUT) / 256, 256, 0, stream>>>(x, w, bias, out);
    }
}